// Round 1
// 498.942 us; speedup vs baseline: 1.0344x; 1.0344x over previous
//
#include <hip/hip_runtime.h>
#include <cmath>
#include <cstdint>
#include <cstddef>

#define NT 17
#define NP 45
#define CH 8
// B=64, S=512, H=768

__device__ __forceinline__ float rlane(float v, int k) {
    return __int_as_float(__builtin_amdgcn_readlane(__float_as_int(v), k));
}

// ---------------------------------------------------------------------------
// Kernel 1: logits = hidden @ [W_tag | W_pos] + bias   (f32 vector GEMM)
// ---------------------------------------------------------------------------
__global__ __launch_bounds__(256) void gemm_logits(
    const float* __restrict__ hidden, const float* __restrict__ Wt,
    const float* __restrict__ bt, const float* __restrict__ Wp,
    const float* __restrict__ bp, float* __restrict__ tagL,
    float* __restrict__ posL)
{
    __shared__ float As[32 * 68];
    __shared__ float Bs[32 * 64];
    const int tid = threadIdx.x;
    const int rg = tid >> 4;
    const int cg = tid & 15;
    const int row0 = blockIdx.x * 64;

    float acc[4][4];
#pragma unroll
    for (int a = 0; a < 4; ++a)
#pragma unroll
        for (int b = 0; b < 4; ++b) acc[a][b] = 0.f;

    for (int kc = 0; kc < 768; kc += 32) {
        __syncthreads();
#pragma unroll
        for (int it = 0; it < 2; ++it) {
            int idx = tid + it * 256;
            int r = idx >> 3, q = idx & 7;
            float4 h = *(const float4*)(hidden + (size_t)(row0 + r) * 768 + kc + q * 4);
            As[(q * 4 + 0) * 68 + r] = h.x;
            As[(q * 4 + 1) * 68 + r] = h.y;
            As[(q * 4 + 2) * 68 + r] = h.z;
            As[(q * 4 + 3) * 68 + r] = h.w;
        }
#pragma unroll
        for (int it = 0; it < 8; ++it) {
            int idx = tid + it * 256;
            int k = idx >> 6, c = idx & 63;
            float v = 0.f;
            if (c < NT) v = Wt[(kc + k) * NT + c];
            else if (c < NT + NP) v = Wp[(kc + k) * NP + (c - NT)];
            Bs[idx] = v;
        }
        __syncthreads();
#pragma unroll
        for (int kk = 0; kk < 32; ++kk) {
            float4 a4 = *(const float4*)(As + kk * 68 + rg * 4);
            float4 b4 = *(const float4*)(Bs + kk * 64 + cg * 4);
            float av[4] = {a4.x, a4.y, a4.z, a4.w};
            float bv[4] = {b4.x, b4.y, b4.z, b4.w};
#pragma unroll
            for (int jr = 0; jr < 4; ++jr)
#pragma unroll
                for (int jc = 0; jc < 4; ++jc)
                    acc[jr][jc] = fmaf(av[jr], bv[jc], acc[jr][jc]);
        }
    }
#pragma unroll
    for (int jr = 0; jr < 4; ++jr) {
        size_t r = (size_t)row0 + rg * 4 + jr;
#pragma unroll
        for (int jc = 0; jc < 4; ++jc) {
            int c = cg * 4 + jc;
            if (c < NT) tagL[r * NT + c] = acc[jr][jc] + bt[c];
            else if (c < NT + NP) posL[r * NP + (c - NT)] = acc[jr][jc] + bp[c - NT];
        }
    }
}

// ---------------------------------------------------------------------------
// Kernel 2: the four CRF scans. One wave per (b, role); 256 blocks x 64 thr.
// The all-to-all broadcast of the state vector is done with v_readlane
// (compile-time lane indices) instead of an LDS write/read round trip: the
// old ds_write -> 12x ds_read_b128 -> fma chain cost ~764 cy/step (latency-
// bound, 1 wave/SIMD, nothing to hide behind); readlane+fma is issue-bound
// at ~200 cy/step. Accumulation order is kept EXACTLY as the LDS version
// (d0..d3 over i mod 4, ((d0+d1)+(d2+d3))*f; padded lanes contribute *0 /
// +(-1e30) identically) so results are bitwise unchanged.
// NLL runs in LINEAR space (f = exp(e) precomputed off-chain per chunk;
// exact power-of-2 rescale per chunk) so the serial chain has no exp/log.
// ---------------------------------------------------------------------------
template <int T, int PAD>
__device__ void nll_scan(int b,
    const float* __restrict__ logits, const int* __restrict__ mask,
    const int* __restrict__ targ, const float* __restrict__ start,
    const float* __restrict__ trans, const float* __restrict__ endv,
    float* __restrict__ den, float* __restrict__ num)
{
    const int lane = threadIdx.x;
    const int jj = (lane < T) ? lane : (T - 1);
    float Ecol[PAD];
#pragma unroll
    for (int i = 0; i < PAD; ++i) Ecol[i] = (i < T) ? __expf(trans[i * T + jj]) : 0.f;
    const float esjj = __expf(start[jj]);
    const float* eptr = logits + (size_t)b * 512 * T + jj;
    const int* mptr = mask + b * 512;

    float eb[CH], en[CH], fb[CH];
    int mb, mn = 0;
#pragma unroll
    for (int k = 0; k < CH; ++k) { eb[k] = eptr[k * T]; en[k] = 0.f; }
    mb = mptr[lane & (CH - 1)];

    float a = 0.f;
    int excorr = 0;
    for (int c = 0; c < 64; ++c) {
        unsigned long long kb = __ballot(mb > 0);
        if (c < 63) {
            const float* ep2 = eptr + (c + 1) * CH * T;
#pragma unroll
            for (int k = 0; k < CH; ++k) en[k] = ep2[k * T];
            mn = mptr[(c + 1) * CH + (lane & (CH - 1))];
        }
#pragma unroll
        for (int k = 0; k < CH; ++k) fb[k] = __expf(eb[k]);   // off-chain
#pragma unroll
        for (int s = 0; s < CH; ++s) {
            // readlane broadcast of a; lanes >= T hold a duplicate of column
            // T-1 and Ecol there is 0, so fma contributes exactly 0.
            float d0 = 0.f, d1 = 0.f, d2 = 0.f, d3 = 0.f;
#pragma unroll
            for (int q = 0; q < PAD / 4; ++q) {
                d0 = fmaf(rlane(a, 4 * q + 0), Ecol[4 * q + 0], d0);
                d1 = fmaf(rlane(a, 4 * q + 1), Ecol[4 * q + 1], d1);
                d2 = fmaf(rlane(a, 4 * q + 2), Ecol[4 * q + 2], d2);
                d3 = fmaf(rlane(a, 4 * q + 3), Ecol[4 * q + 3], d3);
            }
            float cand = ((d0 + d1) + (d2 + d3)) * fb[s];
            bool keep = (kb >> s) & 1ULL;
            bool first = (c == 0) && (s == 0);
            a = first ? (esjj * fb[0]) : (keep ? cand : a);
        }
        // exact power-of-2 rescale (avoids overflow; ~10^24 worst per chunk)
        float m = a;
#pragma unroll
        for (int o = 32; o; o >>= 1) m = fmaxf(m, __shfl_xor(m, o));
        int ex;
        (void)frexpf(m, &ex);
        a *= ldexpf(1.0f, -ex);
        excorr += ex;
#pragma unroll
        for (int k = 0; k < CH; ++k) eb[k] = en[k];
        mb = mn;
    }
    // denominator: log(sum_j a_j * exp(end_j)) + excorr*ln2
    float term = (lane < T) ? a * __expf(endv[lane]) : 0.f;
#pragma unroll
    for (int o = 32; o; o >>= 1) term += __shfl_xor(term, o);
    if (lane == 0) den[b] = __logf(term) + (float)excorr * 0.69314718056f;

    // numerator (raw logits; lse cancels in num-den)
    float part = 0.f; int Lc = 0;
    for (int t = lane; t < 512; t += 64) {
        int mt = mask[b * 512 + t];
        Lc += (mt > 0);
        if (t >= 1 && mt > 0) {
            int tg = targ[b * 512 + t];
            int pg = targ[b * 512 + t - 1];
            part += trans[pg * T + tg] + logits[((size_t)b * 512 + t) * T + tg];
        }
    }
#pragma unroll
    for (int o = 32; o; o >>= 1) { part += __shfl_xor(part, o); Lc += __shfl_xor(Lc, o); }
    if (lane == 0) {
        int t0g = targ[b * 512];
        num[b] = start[t0g] + logits[(size_t)b * 512 * T + t0g]
               + part + endv[targ[b * 512 + Lc - 1]];
    }
}

// Viterbi forward, max only; stores score vectors for later argmax recompute.
// Same readlane broadcast; max is order-exact so scores are bitwise
// unchanged vs the LDS version (hist recompute stays bit-identical).
template <int T, int PAD>
__device__ void vit_fwd(int b,
    const float* __restrict__ logits, const int* __restrict__ mask,
    const float* __restrict__ start, const float* __restrict__ trans,
    float* __restrict__ score)
{
    const int lane = threadIdx.x;
    const int jj = (lane < T) ? lane : (T - 1);
    float Tcol[PAD];
#pragma unroll
    for (int i = 0; i < PAD; ++i) Tcol[i] = (i < T) ? trans[i * T + jj] : -1e30f;
    const float sjj = start[jj];
    const float* eptr = logits + (size_t)b * 512 * T + jj;
    const int* mptr = mask + b * 512;
    float* sptr = score + (size_t)b * 512 * T + lane;

    float eb[CH], en[CH];
    int mb, mn = 0;
#pragma unroll
    for (int k = 0; k < CH; ++k) { eb[k] = eptr[k * T]; en[k] = 0.f; }
    mb = mptr[lane & (CH - 1)];

    float sc = 0.f;
    for (int c = 0; c < 64; ++c) {
        unsigned long long kb = __ballot(mb > 0);
        if (c < 63) {
            const float* ep2 = eptr + (c + 1) * CH * T;
#pragma unroll
            for (int k = 0; k < CH; ++k) en[k] = ep2[k * T];
            mn = mptr[(c + 1) * CH + (lane & (CH - 1))];
        }
#pragma unroll
        for (int s = 0; s < CH; ++s) {
            float m = -1e30f;
#pragma unroll
            for (int q = 0; q < PAD / 4; ++q) {
                float ca = rlane(sc, 4 * q + 0) + Tcol[4 * q + 0];
                float cb = rlane(sc, 4 * q + 1) + Tcol[4 * q + 1];
                float cc = rlane(sc, 4 * q + 2) + Tcol[4 * q + 2];
                float cd = rlane(sc, 4 * q + 3) + Tcol[4 * q + 3];
                m = fmaxf(m, fmaxf(ca, cb));   // -> v_max3
                m = fmaxf(m, fmaxf(cc, cd));
            }
            float nxt = m + eb[s];
            bool keep = (kb >> s) & 1ULL;
            bool first = (c == 0) && (s == 0);
            sc = first ? (sjj + eb[0]) : (keep ? nxt : sc);
            if (lane < T) sptr[(size_t)(c * CH + s) * T] = sc;
        }
#pragma unroll
        for (int k = 0; k < CH; ++k) eb[k] = en[k];
        mb = mn;
    }
}

__global__ __launch_bounds__(64, 1) void scan_kernel(
    const float* tagL, const float* posL, const int* mask,
    const int* tgT, const int* tgP,
    const float* startT, const float* transT, const float* endT,
    const float* startP, const float* transP, const float* endP,
    float* scoreT, float* scoreP,
    float* denT, float* denP, float* numT, float* numP)
{
    int bid = blockIdx.x;
    if (bid < 64)
        vit_fwd<NP, 48>(bid, posL, mask, startP, transP, scoreP);
    else if (bid < 128)
        nll_scan<NP, 48>(bid - 64, posL, mask, tgP, startP, transP, endP, denP, numP);
    else if (bid < 192)
        vit_fwd<NT, 20>(bid - 128, tagL, mask, startT, transT, scoreT);
    else
        nll_scan<NT, 20>(bid - 192, tagL, mask, tgT, startT, transT, endT, denT, numT);
}

// ---------------------------------------------------------------------------
// Kernel 3: recompute Viterbi backpointers massively parallel over (b,t).
// Bit-identical adds vs forward pass => identical argmax.
// ---------------------------------------------------------------------------
template <int T>
__device__ void hist_block(int b, int tc,
    const float* __restrict__ score, const int* __restrict__ mask,
    const float* __restrict__ trans, unsigned char* __restrict__ hist)
{
    const int wave = threadIdx.x >> 6;
    const int lane = threadIdx.x & 63;
    const int jj = (lane < T) ? lane : (T - 1);
    float Tcol[T];
#pragma unroll
    for (int i = 0; i < T; ++i) Tcol[i] = trans[i * T + jj];
    for (int q = 0; q < 16; ++q) {
        int t = tc * 64 + wave * 16 + q;
        if (t < 1) continue;
        int mt = mask[b * 512 + t];
        int hv;
        if (mt > 0) {
            float sv = score[((size_t)b * 512 + t - 1) * T + jj];
            float mx = -1e30f; int am = 0;
#pragma unroll
            for (int i = 0; i < T; ++i) {
                float cand = rlane(sv, i) + Tcol[i];
                bool g = cand > mx;            // strict > keeps FIRST max
                mx = g ? cand : mx;
                am = g ? i : am;
            }
            hv = am;
        } else {
            hv = jj;                           // identity when masked
        }
        if (lane < T)
            hist[((size_t)b * 512 + (t - 1)) * T + lane] = (unsigned char)hv;
    }
}

__global__ __launch_bounds__(256) void hist_kernel(
    const float* scoreT, const float* scoreP, const int* mask,
    const float* transT, const float* transP,
    unsigned char* histT, unsigned char* histP)
{
    int blk = blockIdx.x;
    if (blk < 512) hist_block<NP>(blk >> 3, blk & 7, scoreP, mask, transP, histP);
    else { blk -= 512; hist_block<NT>(blk >> 3, blk & 7, scoreT, mask, transT, histT); }
}

// ---------------------------------------------------------------------------
// Kernel 4: backtrace with pointer-jump composition (serial chain 511 -> 63).
// ---------------------------------------------------------------------------
template <int T>
__device__ void backtrace(int b, const float* __restrict__ score,
    const unsigned char* __restrict__ hist, const float* __restrict__ endv,
    float* __restrict__ outp, unsigned char* sh)
{
    unsigned char* h  = sh;                    // 512*T
    unsigned char* g2 = sh + 512 * T;          // rows 0..509
    unsigned char* g4 = sh + 1024 * T;         // 127 rows (r = 3+4*a4)
    unsigned char* g8 = sh + 1024 * T + 128 * T; // 63 rows (r = 503-8a)
    unsigned char* pr = sh + 1024 * T + 192 * T; // 512
    const int lane = threadIdx.x;

    {   // stage hist to LDS (b-stride = 512*T bytes, 16B multiple)
        const int4* src = (const int4*)(hist + (size_t)b * 512 * T);
        int4* dst = (int4*)h;
        int n16 = (512 * T) / 16;
        for (int i = lane; i < n16; i += 64) dst[i] = src[i];
    }
    __syncthreads();
    // g2[r][i] = h[r][h[r+1][i]]  (maps cur at t=r+2 -> t=r)
    for (int idx = lane; idx < 510 * T; idx += 64) {
        int r = idx / T, i = idx - r * T;
        g2[idx] = h[r * T + h[(r + 1) * T + i]];
    }
    __syncthreads();
    // g4 rows r = 3+4*a4: g4[a4][i] = g2[r][ g2[r+2][i] ]  (t=r+4 -> r)
    for (int idx = lane; idx < 127 * T; idx += 64) {
        int a4 = idx / T, i = idx - a4 * T;
        int r = 3 + 4 * a4;
        g4[idx] = g2[r * T + g2[(r + 2) * T + i]];
    }
    __syncthreads();
    // g8 rows r = 503-8a: g8[a][i] = g4row(r)[ g4row(r+4)[i] ]  (t=r+8 -> r)
    for (int idx = lane; idx < 63 * T; idx += 64) {
        int a = idx / T, i = idx - a * T;
        int r = 503 - 8 * a;
        int a4lo = (r - 3) >> 2, a4hi = (r + 1) >> 2;
        g8[idx] = g4[a4lo * T + g4[a4hi * T + i]];
    }
    // last = first-index argmax(score[511] + end)
    float v = (lane < T) ? (score[((size_t)b * 512 + 511) * T + lane] + endv[lane]) : -1e30f;
    float mx = v;
#pragma unroll
    for (int o = 32; o; o >>= 1) mx = fmaxf(mx, __shfl_xor(mx, o));
    unsigned long long bal = __ballot(v == mx);
    int cur = __ffsll(bal) - 1;
    __syncthreads();
    // phase A: serial anchor chain, 63 dependent LDS reads
    int myCur = 0;
    for (int a = 0; a < 64; ++a) {
        if (lane == a) myCur = cur;
        if (a < 63) cur = g8[a * T + cur];
    }
    // phase B: each lane fills its 8-step segment
    {
        int ta = 511 - 8 * lane;
        int j = myCur;
        pr[ta] = (unsigned char)j;
        int rlo = (lane == 63) ? 0 : (ta - 7);
        for (int r = ta - 1; r >= rlo; --r) {
            j = h[r * T + j];
            pr[r] = (unsigned char)j;
        }
    }
    __syncthreads();
    for (int k = lane; k < 512; k += 64)
        outp[(size_t)b * 512 + k] = (float)pr[k];
}

__global__ __launch_bounds__(64, 1) void backtrace_kernel(
    const float* scoreT, const float* scoreP,
    const unsigned char* histT, const unsigned char* histP,
    const float* endT, const float* endP, float* out)
{
    __shared__ __align__(16) unsigned char sh[1216 * NP + 576];
    int blk = blockIdx.x;
    if (blk < 64) backtrace<NP>(blk, scoreP, histP, endP, out + 32768, sh);
    else backtrace<NT>(blk - 64, scoreT, histT, endT, out, sh);
}

// ---------------------------------------------------------------------------
// Kernel 5: losses = -mean(num - den)
// ---------------------------------------------------------------------------
__global__ __launch_bounds__(64) void finalize_kernel(
    const float* numT, const float* denT, const float* numP, const float* denP,
    float* out)
{
    int lane = threadIdx.x;
    float dT = numT[lane] - denT[lane];
    float dP = numP[lane] - denP[lane];
#pragma unroll
    for (int o = 32; o; o >>= 1) { dT += __shfl_xor(dT, o); dP += __shfl_xor(dP, o); }
    if (lane == 0) {
        out[65536] = -dT / 64.f;
        out[65537] = -dP / 64.f;
    }
}

// ---------------------------------------------------------------------------
extern "C" void kernel_launch(void* const* d_in, const int* in_sizes, int n_in,
                              void* d_out, int out_size, void* d_ws, size_t ws_size,
                              hipStream_t stream)
{
    const float* hidden = (const float*)d_in[0];
    const int*   mask   = (const int*)d_in[1];
    const int*   tgT    = (const int*)d_in[2];
    const int*   tgP    = (const int*)d_in[3];
    const float* Wt     = (const float*)d_in[4];
    const float* bt     = (const float*)d_in[5];
    const float* Wp     = (const float*)d_in[6];
    const float* bp     = (const float*)d_in[7];
    const float* startT = (const float*)d_in[8];
    const float* transT = (const float*)d_in[9];
    const float* endT   = (const float*)d_in[10];
    const float* startP = (const float*)d_in[11];
    const float* transP = (const float*)d_in[12];
    const float* endP   = (const float*)d_in[13];

    float* ws     = (float*)d_ws;
    float* tagL   = ws;                         // 557056
    float* posL   = tagL + 557056;              // 1474560
    float* scoreT = posL + 1474560;             // 557056
    float* scoreP = scoreT + 557056;            // 1474560
    float* denT   = scoreP + 1474560;           // 64
    float* denP   = denT + 64;
    float* numT   = denP + 64;
    float* numP   = numT + 64;
    unsigned char* histT = (unsigned char*)(numP + 64);       // 64*512*17 B
    unsigned char* histP = histT + (size_t)64 * 512 * NT;     // 64*512*45 B
    float* out = (float*)d_out;

    gemm_logits<<<512, 256, 0, stream>>>(hidden, Wt, bt, Wp, bp, tagL, posL);
    scan_kernel<<<256, 64, 0, stream>>>(tagL, posL, mask, tgT, tgP,
        startT, transT, endT, startP, transP, endP,
        scoreT, scoreP, denT, denP, numT, numP);
    hist_kernel<<<1024, 256, 0, stream>>>(scoreT, scoreP, mask, transT, transP,
        histT, histP);
    backtrace_kernel<<<128, 64, 0, stream>>>(scoreT, scoreP, histT, histP,
        endT, endP, out);
    finalize_kernel<<<1, 64, 0, stream>>>(numT, denT, numP, denP, out);
}